// Round 12
// baseline (448.337 us; speedup 1.0000x reference)
//
#include <hip/hip_runtime.h>
#include <math.h>

#define DD 128
#define HH 16
#define EPSV 1e-5f

static __device__ __forceinline__ ushort f2bf(float f) {
  uint u = __float_as_uint(f);
  u += 0x7FFFu + ((u >> 16) & 1u);
  return (ushort)(u >> 16);
}
static __device__ __forceinline__ float bflo(uint u) { return __uint_as_float(u << 16); }
static __device__ __forceinline__ float bfhi(uint u) { return __uint_as_float(u & 0xFFFF0000u); }

// ---------------- scans (padded-to-8 degrees) ----------------

#define SCAN_T 1024
#define SCAN_I 4

__global__ void k_scan1(const int* __restrict__ deg, int* __restrict__ bsum, int n) {
  __shared__ int sh[SCAN_T];
  int tid = threadIdx.x;
  int base = blockIdx.x * SCAN_T * SCAN_I + tid * SCAN_I;
  int s = 0;
#pragma unroll
  for (int j = 0; j < SCAN_I; ++j) {
    int i = base + j;
    if (i < n) s += (deg[i] + 7) & ~7;
  }
  sh[tid] = s;
  __syncthreads();
  for (int off = SCAN_T / 2; off > 0; off >>= 1) {
    if (tid < off) sh[tid] += sh[tid + off];
    __syncthreads();
  }
  if (tid == 0) bsum[blockIdx.x] = sh[0];
}

// scan2: padded exclusive prefix -> rowoff & cursor; dinv; pad entries (=n) into csr32
__global__ void k_scan2(const int* __restrict__ deg, const int* __restrict__ bsum,
                        int* __restrict__ rowoff, int* __restrict__ cursor,
                        float* __restrict__ dinv, uint* __restrict__ csr32, int n) {
  __shared__ int sh[SCAN_T];
  __shared__ int sbase;
  int tid = threadIdx.x;
  int b = blockIdx.x;
  if (tid == 0) { int s = 0; for (int j = 0; j < b; ++j) s += bsum[j]; sbase = s; }
  int base = b * SCAN_T * SCAN_I + tid * SCAN_I;
  int d[SCAN_I], dp[SCAN_I]; int ts = 0;
#pragma unroll
  for (int j = 0; j < SCAN_I; ++j) {
    int i = base + j;
    d[j] = (i < n) ? deg[i] : 0;
    dp[j] = (d[j] + 7) & ~7;
    ts += dp[j];
  }
  sh[tid] = ts;
  __syncthreads();
  for (int off = 1; off < SCAN_T; off <<= 1) {
    int v = (tid >= off) ? sh[tid - off] : 0;
    __syncthreads();
    sh[tid] += v;
    __syncthreads();
  }
  int ex = sbase + sh[tid] - ts;
#pragma unroll
  for (int j = 0; j < SCAN_I; ++j) {
    int i = base + j;
    if (i < n) {
      rowoff[i] = ex;
      cursor[i] = ex;
      dinv[i] = rsqrtf((float)d[j] + 2.0f);
      for (int k = d[j]; k < dp[j]; ++k) csr32[ex + k] = (uint)n;  // pad -> zero row
    }
    ex += dp[j];
    if (i == n - 1) rowoff[n] = ex;
  }
}

// fill: plain 4B scattered stores (L2-absorbed)
__global__ void k_fill(const int* __restrict__ src, const int* __restrict__ dst,
                       int* __restrict__ cursor, uint* __restrict__ csr32, int ecnt) {
  int e = blockIdx.x * blockDim.x + threadIdx.x;
  if (e >= ecnt) return;
  int s = src[e], d = dst[e];
  int idx = atomicAdd(&cursor[d], 1);
  csr32[idx] = (uint)s;
}

// pack: csr16[k] = lo16(csr32[2k]) | lo16(csr32[2k+1])<<16  (sequential streams)
__global__ void k_pack(const uint* __restrict__ csr32, uint* __restrict__ csr16,
                       const int* __restrict__ rowoff, int n) {
  int tot = rowoff[n];                 // multiple of 8
  int k = blockIdx.x * blockDim.x + threadIdx.x;
  if (k < (tot >> 1)) {
    uint a = csr32[2 * k], bq = csr32[2 * k + 1];
    csr16[k] = (a & 0xFFFFu) | (bq << 16);
  }
}

// ---------------- GEMM1 (fp32 A, xdinv epilogue) fused with degree histogram ----------

static __device__ __forceinline__ void gemm_f32_body(
    const float* __restrict__ A, const float* __restrict__ B,
    const float* __restrict__ dinv, ushort* __restrict__ C, int nrows, int bx,
    float* Bs) {
  int tid = threadIdx.x;
  int tx = tid & 15, ty = tid >> 4;
  int rowbase = (bx >> 1) * 128;
  int c0 = (bx & 1) * 64;
  {
    int kk = tid >> 4;
    int cc = (tid & 15) * 4;
#pragma unroll
    for (int p = 0; p < 8; ++p) {
      int k = p * 16 + kk;
      float4 bv = *reinterpret_cast<const float4*>(&B[k * DD + c0 + cc]);
      *reinterpret_cast<float4*>(&Bs[k * 64 + cc]) = bv;
    }
  }
  __syncthreads();
  float acc[8][4];
#pragma unroll
  for (int i = 0; i < 8; ++i)
#pragma unroll
    for (int j = 0; j < 4; ++j) acc[i][j] = 0.f;
  int rl[8];
#pragma unroll
  for (int i = 0; i < 8; ++i) {
    int r = rowbase + ty * 8 + i;
    rl[i] = (r < nrows) ? r : (nrows - 1);
  }
  const float4* A4 = reinterpret_cast<const float4*>(A);
  for (int kq = 0; kq < 32; ++kq) {
    float4 av[8];
#pragma unroll
    for (int i = 0; i < 8; ++i) av[i] = A4[(size_t)rl[i] * 32 + kq];
#pragma unroll
    for (int j = 0; j < 4; ++j) {
      float4 bv = *reinterpret_cast<const float4*>(&Bs[(kq * 4 + j) * 64 + tx * 4]);
#pragma unroll
      for (int i = 0; i < 8; ++i) {
        float a = (j == 0) ? av[i].x : (j == 1) ? av[i].y : (j == 2) ? av[i].z : av[i].w;
        acc[i][0] = fmaf(a, bv.x, acc[i][0]);
        acc[i][1] = fmaf(a, bv.y, acc[i][1]);
        acc[i][2] = fmaf(a, bv.z, acc[i][2]);
        acc[i][3] = fmaf(a, bv.w, acc[i][3]);
      }
    }
  }
  int cbase = c0 + tx * 4;
#pragma unroll
  for (int i = 0; i < 8; ++i) {
    int r = rowbase + ty * 8 + i;
    if (r < nrows) {
      float dv = dinv[r];
      ushort4 o;
      o.x = f2bf(acc[i][0] * dv); o.y = f2bf(acc[i][1] * dv);
      o.z = f2bf(acc[i][2] * dv); o.w = f2bf(acc[i][3] * dv);
      *reinterpret_cast<ushort4*>(&C[(size_t)r * DD + cbase]) = o;
    }
  }
}

__global__ __launch_bounds__(256) void k_gemm1_hist(
    const float* __restrict__ A, const float* __restrict__ B,
    const float* __restrict__ dinv, ushort* __restrict__ C, int nrows,
    const int* __restrict__ dst, int* __restrict__ deg, int ecnt,
    int gblocks, int hblocks) {
  __shared__ float Bs[DD * 64];
  int bx = blockIdx.x;
  if (bx < gblocks) {
    gemm_f32_body(A, B, dinv, C, nrows, bx, Bs);
  } else {
    int stride = hblocks * 256;
    for (int e = (bx - gblocks) * 256 + threadIdx.x; e < ecnt; e += stride)
      atomicAdd(&deg[dst[e]], 1);
  }
}

// NOTE: gemm1 needs dinv (from scan2) for its epilogue, but hist must run BEFORE scans.
// So gemm1_hist's gemm part cannot use dinv... -> split: histogram first (fused with a
// plain GEMM that writes un-scaled xw), then a tiny scale pass? Instead: keep dinv
// folding by running GEMM1 AFTER scan2 (it's a dependency: scan2 -> gemm1). Hist is
// fused into GEMM1's grid but hist writes deg which scan1 needs -- conflict.
// Resolution used here: hist runs standalone first; GEMM1 (with dinv epilogue) runs
// after scan2, fused with nothing. Fill runs after scan2 as well.

__global__ __launch_bounds__(256) void k_gemm1(
    const float* __restrict__ A, const float* __restrict__ B,
    const float* __restrict__ dinv, ushort* __restrict__ C, int nrows) {
  __shared__ float Bs[DD * 64];
  gemm_f32_body(A, B, dinv, C, nrows, blockIdx.x, Bs);
}

__global__ void k_hist(const int* __restrict__ dst, int* __restrict__ deg, int ecnt) {
  int stride = gridDim.x * blockDim.x;
  for (int e = blockIdx.x * blockDim.x + threadIdx.x; e < ecnt; e += stride)
    atomicAdd(&deg[dst[e]], 1);
}

// ---------------- GEMM2: bf16 A @ f32 B, xdinv epilogue -> bf16 ----------------

__global__ __launch_bounds__(256) void k_gemmb(const ushort* __restrict__ A,
                                               const float* __restrict__ B,
                                               const float* __restrict__ dinv,
                                               ushort* __restrict__ C, int nrows) {
  __shared__ float Bs[DD * 64];
  int tid = threadIdx.x;
  int tx = tid & 15, ty = tid >> 4;
  int rowbase = (blockIdx.x >> 1) * 128;
  int c0 = (blockIdx.x & 1) * 64;
  {
    int kk = tid >> 4;
    int cc = (tid & 15) * 4;
#pragma unroll
    for (int p = 0; p < 8; ++p) {
      int k = p * 16 + kk;
      float4 bv = *reinterpret_cast<const float4*>(&B[k * DD + c0 + cc]);
      *reinterpret_cast<float4*>(&Bs[k * 64 + cc]) = bv;
    }
  }
  __syncthreads();
  float acc[8][4];
#pragma unroll
  for (int i = 0; i < 8; ++i)
#pragma unroll
    for (int j = 0; j < 4; ++j) acc[i][j] = 0.f;
  int rl[8];
#pragma unroll
  for (int i = 0; i < 8; ++i) {
    int r = rowbase + ty * 8 + i;
    rl[i] = (r < nrows) ? r : (nrows - 1);
  }
  const uint4* A16 = reinterpret_cast<const uint4*>(A);  // 16B = 8 bf16
  for (int kq = 0; kq < 16; ++kq) {
    uint4 av[8];
#pragma unroll
    for (int i = 0; i < 8; ++i) av[i] = A16[(size_t)rl[i] * 16 + kq];
#pragma unroll
    for (int kk = 0; kk < 8; ++kk) {
      float4 bv = *reinterpret_cast<const float4*>(&Bs[(kq * 8 + kk) * 64 + tx * 4]);
#pragma unroll
      for (int i = 0; i < 8; ++i) {
        uint wq = (kk < 2) ? av[i].x : (kk < 4) ? av[i].y : (kk < 6) ? av[i].z : av[i].w;
        float a = (kk & 1) ? bfhi(wq) : bflo(wq);
        acc[i][0] = fmaf(a, bv.x, acc[i][0]);
        acc[i][1] = fmaf(a, bv.y, acc[i][1]);
        acc[i][2] = fmaf(a, bv.z, acc[i][2]);
        acc[i][3] = fmaf(a, bv.w, acc[i][3]);
      }
    }
  }
  int cbase = c0 + tx * 4;
#pragma unroll
  for (int i = 0; i < 8; ++i) {
    int r = rowbase + ty * 8 + i;
    if (r < nrows) {
      float dv = dinv[r];
      ushort4 o;
      o.x = f2bf(acc[i][0] * dv); o.y = f2bf(acc[i][1] * dv);
      o.z = f2bf(acc[i][2] * dv); o.w = f2bf(acc[i][3] * dv);
      *reinterpret_cast<ushort4*>(&C[(size_t)r * DD + cbase]) = o;
    }
  }
}

// ---------------- edge accumulate: unweighted gather-sum, u16 CSR ----------------

static __device__ __forceinline__ void edge_accum(
    const uint* __restrict__ xw32, const ushort* __restrict__ csr,
    int start, int cnt, uint lane, float& acc0, float& acc1) {
  const uint4* cs = (const uint4*)(csr + __builtin_amdgcn_readfirstlane(start));
  int rem = __builtin_amdgcn_readfirstlane(cnt);
  uint4 c;
  if (rem >= 8) c = *cs++;
  while (rem >= 16) {
    uint v[8];
    v[0] = xw32[((c.x & 0xFFFFu) << 6) + lane];
    v[1] = xw32[((c.x >> 16) << 6) + lane];
    v[2] = xw32[((c.y & 0xFFFFu) << 6) + lane];
    v[3] = xw32[((c.y >> 16) << 6) + lane];
    v[4] = xw32[((c.z & 0xFFFFu) << 6) + lane];
    v[5] = xw32[((c.z >> 16) << 6) + lane];
    v[6] = xw32[((c.w & 0xFFFFu) << 6) + lane];
    v[7] = xw32[((c.w >> 16) << 6) + lane];
    uint4 cn = *cs++;
#pragma unroll
    for (int j = 0; j < 8; ++j) {
      acc0 += bflo(v[j]);
      acc1 += bfhi(v[j]);
    }
    c = cn; rem -= 8;
  }
  if (rem >= 8) {
    uint v[8];
    v[0] = xw32[((c.x & 0xFFFFu) << 6) + lane];
    v[1] = xw32[((c.x >> 16) << 6) + lane];
    v[2] = xw32[((c.y & 0xFFFFu) << 6) + lane];
    v[3] = xw32[((c.y >> 16) << 6) + lane];
    v[4] = xw32[((c.z & 0xFFFFu) << 6) + lane];
    v[5] = xw32[((c.z >> 16) << 6) + lane];
    v[6] = xw32[((c.w & 0xFFFFu) << 6) + lane];
    v[7] = xw32[((c.w >> 16) << 6) + lane];
#pragma unroll
    for (int j = 0; j < 8; ++j) {
      acc0 += bflo(v[j]);
      acc1 += bfhi(v[j]);
    }
  }
}

// ---------------- agg1: gather-sum + di scale + bias + LN + ReLU -> bf16 h1 ------------

__global__ __launch_bounds__(256) void k_agg1(
    const ushort* __restrict__ xwd, const ushort* __restrict__ csr,
    const int* __restrict__ rowoff, const float* __restrict__ dinv,
    const float* __restrict__ bias, const float* __restrict__ gam,
    const float* __restrict__ bet, uint* __restrict__ outp, int n) {
  int wv = threadIdx.x >> 6, lane = threadIdx.x & 63;
  int i = blockIdx.x * 4 + wv;
  if (i >= n) return;
  int start = rowoff[i], cnt = rowoff[i + 1] - start;
  float di = dinv[i];
  const uint* xw32 = (const uint*)xwd;
  float acc0 = 0.f, acc1 = 0.f;
  edge_accum(xw32, csr, start, cnt, (uint)lane, acc0, acc1);
  uint su = xw32[((uint)i << 6) + lane];
  float2 bv = ((const float2*)bias)[lane];
  float c0v = fmaf(di, acc0 + 2.f * bflo(su), bv.x);
  float c1v = fmaf(di, acc1 + 2.f * bfhi(su), bv.y);
  float s = c0v + c1v;
#pragma unroll
  for (int off = 32; off > 0; off >>= 1) s += __shfl_xor(s, off);
  float mu = s * (1.f / DD);
  float c0 = c0v - mu, c1 = c1v - mu;
  float q = c0 * c0 + c1 * c1;
#pragma unroll
  for (int off = 32; off > 0; off >>= 1) q += __shfl_xor(q, off);
  float rstd = rsqrtf(q * (1.f / DD) + EPSV);
  float2 gv = ((const float2*)gam)[lane];
  float2 tv = ((const float2*)bet)[lane];
  float h0 = fmaxf(fmaf(c0 * rstd, gv.x, tv.x), 0.f);
  float h1 = fmaxf(fmaf(c1 * rstd, gv.y, tv.y), 0.f);
  uint packed = (uint)f2bf(h0) | ((uint)f2bf(h1) << 16);
  __builtin_nontemporal_store(packed, &outp[((uint)i << 6) + lane]);
}

// ---------------- agg2: gather-sum + LN + SE + residual + ReLU -> fp32 out -------------

__global__ __launch_bounds__(256) void k_agg2(
    const ushort* __restrict__ xwd, const ushort* __restrict__ csr,
    const int* __restrict__ rowoff, const float* __restrict__ dinv,
    const float* __restrict__ bias, const float* __restrict__ gam,
    const float* __restrict__ bet, const float* __restrict__ Ws,
    const float* __restrict__ bs, const float* __restrict__ We,
    const float* __restrict__ be, const float* __restrict__ xin,
    float* __restrict__ outp, int n) {
  int wv = threadIdx.x >> 6, lane = threadIdx.x & 63;
  int i = blockIdx.x * 4 + wv;
  if (i >= n) return;
  int start = rowoff[i], cnt = rowoff[i + 1] - start;
  float di = dinv[i];
  const uint* xw32 = (const uint*)xwd;
  float acc0 = 0.f, acc1 = 0.f;
  edge_accum(xw32, csr, start, cnt, (uint)lane, acc0, acc1);
  uint su = xw32[((uint)i << 6) + lane];
  float2 bv = ((const float2*)bias)[lane];
  float c0v = fmaf(di, acc0 + 2.f * bflo(su), bv.x);
  float c1v = fmaf(di, acc1 + 2.f * bfhi(su), bv.y);
  float s = c0v + c1v;
#pragma unroll
  for (int off = 32; off > 0; off >>= 1) s += __shfl_xor(s, off);
  float mu = s * (1.f / DD);
  float c0 = c0v - mu, c1 = c1v - mu;
  float q = c0 * c0 + c1 * c1;
#pragma unroll
  for (int off = 32; off > 0; off >>= 1) q += __shfl_xor(q, off);
  float rstd = rsqrtf(q * (1.f / DD) + EPSV);
  float2 gv = ((const float2*)gam)[lane];
  float2 tv = ((const float2*)bet)[lane];
  float h0 = fmaf(c0 * rstd, gv.x, tv.x);
  float h1 = fmaf(c1 * rstd, gv.y, tv.y);
  float pj[HH];
  const float* wr0 = &Ws[(2 * lane) * HH];
  const float* wr1 = &Ws[(2 * lane + 1) * HH];
#pragma unroll
  for (int j = 0; j < HH; ++j) pj[j] = h0 * wr0[j] + h1 * wr1[j];
#pragma unroll
  for (int off = 32; off > 0; off >>= 1) {
#pragma unroll
    for (int j = 0; j < HH; ++j) pj[j] += __shfl_xor(pj[j], off);
  }
  float2 bev = ((const float2*)be)[lane];
  float wacc0 = bev.x, wacc1 = bev.y;
#pragma unroll
  for (int j = 0; j < HH; ++j) {
    float sj = fmaxf(pj[j] + bs[j], 0.f);
    float2 wev = ((const float2*)(We + j * DD))[lane];
    wacc0 = fmaf(sj, wev.x, wacc0);
    wacc1 = fmaf(sj, wev.y, wacc1);
  }
  float w0 = 1.f / (1.f + __expf(-wacc0));
  float w1 = 1.f / (1.f + __expf(-wacc1));
  float2 xr = ((const float2*)(xin + (size_t)i * DD))[lane];
  float2 o;
  o.x = fmaxf(fmaf(h0, w0, xr.x), 0.f);
  o.y = fmaxf(fmaf(h1, w1, xr.y), 0.f);
  ((float2*)(outp + (size_t)i * DD))[lane] = o;
}

// ---------------- launcher ----------------

extern "C" void kernel_launch(void* const* d_in, const int* in_sizes, int n_in,
                              void* d_out, int out_size, void* d_ws, size_t ws_size,
                              hipStream_t stream) {
  const float* x   = (const float*)d_in[0];
  const int*   ei  = (const int*)d_in[1];
  const float* W1  = (const float*)d_in[2];
  const float* b1  = (const float*)d_in[3];
  const float* g1  = (const float*)d_in[4];
  const float* be1 = (const float*)d_in[5];
  const float* W2  = (const float*)d_in[6];
  const float* b2  = (const float*)d_in[7];
  const float* g2  = (const float*)d_in[8];
  const float* be2 = (const float*)d_in[9];
  const float* Ws  = (const float*)d_in[10];
  const float* bs  = (const float*)d_in[11];
  const float* We  = (const float*)d_in[12];
  const float* bee = (const float*)d_in[13];
  float* outp = (float*)d_out;

  int n    = in_sizes[0] / DD;
  int ecnt = in_sizes[1] / 2;
  const int* src = ei;
  const int* dst = ei + ecnt;

  size_t maxent = (size_t)ecnt + 8 * (size_t)n + 64;

  char* w = (char*)d_ws;
  ushort* xwd   = (ushort*)w; w += (size_t)(n + 1) * DD * 2;  // row n = zero row
  uint*   h1    = (uint*)w;   w += (size_t)n * DD * 2;        // bf16 packed
  int*    deg   = (int*)w;    w += (size_t)n * 4;
  int*    cursor= (int*)w;    w += (size_t)n * 4;
  int*    rowoff= (int*)w;    w += (size_t)(n + 1) * 4;
  float*  dinv  = (float*)w;  w += (size_t)n * 4;
  int*    bsum  = (int*)w;    w += 64 * 4;
  w = (char*)(((size_t)w + 15) & ~(size_t)15);
  uint*   csr32 = (uint*)w;   w += maxent * 4;
  w = (char*)(((size_t)w + 15) & ~(size_t)15);
  ushort* csr   = (ushort*)w; w += maxent * 2;

  hipMemsetAsync(deg, 0, (size_t)n * 4, stream);
  hipMemsetAsync(xwd + (size_t)n * DD, 0, DD * 2, stream);  // zero row

  const int TB = 256;
  k_hist<<<2048, TB, 0, stream>>>(dst, deg, ecnt);
  int nb = (n + SCAN_T * SCAN_I - 1) / (SCAN_T * SCAN_I);
  k_scan1<<<nb, SCAN_T, 0, stream>>>(deg, bsum, n);
  k_scan2<<<nb, SCAN_T, 0, stream>>>(deg, bsum, rowoff, cursor, dinv, csr32, n);

  int gblocks = ((n + 127) / 128) * 2;
  int eb = (ecnt + TB - 1) / TB;
  k_gemm1<<<gblocks, TB, 0, stream>>>(x, W1, dinv, xwd, n);
  k_fill<<<eb, TB, 0, stream>>>(src, dst, cursor, csr32, ecnt);
  int pb = (int)((maxent / 2 + TB - 1) / TB);
  k_pack<<<pb, TB, 0, stream>>>(csr32, (uint*)csr, rowoff, n);

  int nb4 = (n + 3) / 4;
  k_agg1<<<nb4, TB, 0, stream>>>(xwd, csr, rowoff, dinv, b1, g1, be1, h1, n);
  k_gemmb<<<gblocks, TB, 0, stream>>>((const ushort*)h1, W2, dinv, xwd, n);
  k_agg2<<<nb4, TB, 0, stream>>>(xwd, csr, rowoff, dinv, b2, g2, be2,
                                 Ws, bs, We, bee, x, outp, n);
}

// Round 13
// 326.700 us; speedup vs baseline: 1.3723x; 1.3723x over previous
//
#include <hip/hip_runtime.h>
#include <math.h>

#define DD 128
#define HH 16
#define NB 256      // dst-range buckets
#define TILE 8192   // edges per pass-A tile
#define SEGCAP 24576
#define EPSV 1e-5f

typedef unsigned long long u64;

static __device__ __forceinline__ ushort f2bf(float f) {
  uint u = __float_as_uint(f);
  u += 0x7FFFu + ((u >> 16) & 1u);
  return (ushort)(u >> 16);
}
static __device__ __forceinline__ float bflo(uint u) { return __uint_as_float(u << 16); }
static __device__ __forceinline__ float bfhi(uint u) { return __uint_as_float(u & 0xFFFF0000u); }

// ---------------- degree histogram ----------------

__global__ void k_hist(const int* __restrict__ dst, int* __restrict__ deg, int ecnt) {
  int stride = gridDim.x * blockDim.x;
  for (int e = blockIdx.x * blockDim.x + threadIdx.x; e < ecnt; e += stride)
    atomicAdd(&deg[dst[e]], 1);
}

// ---------------- scans: packed (padded<<32 | raw) ----------------

#define SCAN_T 1024
#define SCAN_I 4

__global__ void k_scan1(const int* __restrict__ deg, u64* __restrict__ bsum, int n) {
  __shared__ u64 sh[SCAN_T];
  int tid = threadIdx.x;
  int base = blockIdx.x * SCAN_T * SCAN_I + tid * SCAN_I;
  u64 s = 0;
#pragma unroll
  for (int j = 0; j < SCAN_I; ++j) {
    int i = base + j;
    if (i < n) {
      int d = deg[i];
      int dp = (d + 7) & ~7;
      s += ((u64)dp << 32) | (u64)(uint)d;
    }
  }
  sh[tid] = s;
  __syncthreads();
  for (int off = SCAN_T / 2; off > 0; off >>= 1) {
    if (tid < off) sh[tid] += sh[tid + off];
    __syncthreads();
  }
  if (tid == 0) bsum[blockIdx.x] = sh[0];
}

__global__ void k_scan2(const int* __restrict__ deg, const u64* __restrict__ bsum,
                        int* __restrict__ rowoff, int* __restrict__ cursor,
                        int* __restrict__ bucketBase, int* __restrict__ bucketCur,
                        int n) {
  __shared__ u64 sh[SCAN_T];
  __shared__ u64 sbase;
  int tid = threadIdx.x;
  int b = blockIdx.x;
  if (tid == 0) { u64 s = 0; for (int j = 0; j < b; ++j) s += bsum[j]; sbase = s; }
  int base = b * SCAN_T * SCAN_I + tid * SCAN_I;
  int d[SCAN_I]; u64 ts = 0;
#pragma unroll
  for (int j = 0; j < SCAN_I; ++j) {
    int i = base + j;
    d[j] = (i < n) ? deg[i] : 0;
    int dp = (d[j] + 7) & ~7;
    ts += ((u64)dp << 32) | (u64)(uint)d[j];
  }
  sh[tid] = ts;
  __syncthreads();
  for (int off = 1; off < SCAN_T; off <<= 1) {
    u64 v = (tid >= off) ? sh[tid - off] : 0;
    __syncthreads();
    sh[tid] += v;
    __syncthreads();
  }
  u64 ex = sbase + sh[tid] - ts;
#pragma unroll
  for (int j = 0; j < SCAN_I; ++j) {
    int i = base + j;
    if (i < n) {
      int ro = (int)(ex >> 32);
      int raw = (int)(ex & 0xFFFFFFFFu);
      rowoff[i] = ro;
      cursor[i] = ro;
      int bq = (int)(((uint)i * NB) / (uint)n);
      if (i == (bq * n + NB - 1) / NB) { bucketBase[bq] = raw; bucketCur[bq] = raw; }
      int dp = (d[j] + 7) & ~7;
      ex += ((u64)dp << 32) | (u64)(uint)d[j];
      if (i == n - 1) rowoff[n] = (int)(ex >> 32);
    }
  }
}

// ---------------- GEMM fp32 body (dinv-from-deg epilogue) ----------------

static __device__ __forceinline__ void gemm_f32_body(
    const float* __restrict__ A, const float* __restrict__ B,
    const int* __restrict__ deg, ushort* __restrict__ C, int nrows, int bx,
    float* Bs) {
  int tid = threadIdx.x;
  int tx = tid & 15, ty = tid >> 4;
  int rowbase = (bx >> 1) * 128;
  int c0 = (bx & 1) * 64;
  {
    int kk = tid >> 4;
    int cc = (tid & 15) * 4;
#pragma unroll
    for (int p = 0; p < 8; ++p) {
      int k = p * 16 + kk;
      float4 bv = *reinterpret_cast<const float4*>(&B[k * DD + c0 + cc]);
      *reinterpret_cast<float4*>(&Bs[k * 64 + cc]) = bv;
    }
  }
  __syncthreads();
  float acc[8][4];
#pragma unroll
  for (int i = 0; i < 8; ++i)
#pragma unroll
    for (int j = 0; j < 4; ++j) acc[i][j] = 0.f;
  int rl[8];
#pragma unroll
  for (int i = 0; i < 8; ++i) {
    int r = rowbase + ty * 8 + i;
    rl[i] = (r < nrows) ? r : (nrows - 1);
  }
  const float4* A4 = reinterpret_cast<const float4*>(A);
  for (int kq = 0; kq < 32; ++kq) {
    float4 av[8];
#pragma unroll
    for (int i = 0; i < 8; ++i) av[i] = A4[(size_t)rl[i] * 32 + kq];
#pragma unroll
    for (int j = 0; j < 4; ++j) {
      float4 bv = *reinterpret_cast<const float4*>(&Bs[(kq * 4 + j) * 64 + tx * 4]);
#pragma unroll
      for (int i = 0; i < 8; ++i) {
        float a = (j == 0) ? av[i].x : (j == 1) ? av[i].y : (j == 2) ? av[i].z : av[i].w;
        acc[i][0] = fmaf(a, bv.x, acc[i][0]);
        acc[i][1] = fmaf(a, bv.y, acc[i][1]);
        acc[i][2] = fmaf(a, bv.z, acc[i][2]);
        acc[i][3] = fmaf(a, bv.w, acc[i][3]);
      }
    }
  }
  int cbase = c0 + tx * 4;
#pragma unroll
  for (int i = 0; i < 8; ++i) {
    int r = rowbase + ty * 8 + i;
    if (r < nrows) {
      float dv = rsqrtf((float)deg[r] + 2.0f);
      ushort4 o;
      o.x = f2bf(acc[i][0] * dv); o.y = f2bf(acc[i][1] * dv);
      o.z = f2bf(acc[i][2] * dv); o.w = f2bf(acc[i][3] * dv);
      *reinterpret_cast<ushort4*>(&C[(size_t)r * DD + cbase]) = o;
    }
  }
}

// ---------------- GEMM1 fused with pass-A bucket scatter ----------------
// blocks [0, abloks): bucket-scatter tiles; blocks [abloks, abloks+gblocks): GEMM.

__global__ __launch_bounds__(256) void k_gemm1_bucket(
    const float* __restrict__ A, const float* __restrict__ B,
    const int* __restrict__ deg, ushort* __restrict__ C, int nrows,
    const int* __restrict__ src, const int* __restrict__ dst,
    int* __restrict__ bucketCur, uint* __restrict__ pairs, int ecnt,
    int abloks, int gblocks) {
  __shared__ uint smem[8960];  // 35 KB: staging 8192 + cnt 256 + gbase 256 + cur 256
  int bx = blockIdx.x;
  if (bx >= abloks) {
    gemm_f32_body(A, B, deg, C, nrows, bx - abloks, (float*)smem);
    return;
  }
  uint* stag  = smem;          // [8192]
  uint* cnt   = smem + 8192;   // [256] counts -> local excl offsets
  uint* gbase = smem + 8448;   // [256]
  uint* cur   = smem + 8704;   // [256]
  int tid = threadIdx.x;
  int ntiles = (ecnt + TILE - 1) / TILE;
  for (int t = bx; t < ntiles; t += abloks) {
    int base = t * TILE;
    int cntE = min(TILE, ecnt - base);
    cnt[tid] = 0;
    __syncthreads();
    // phase 1: histogram buckets
    for (int k = tid; k < cntE; k += 256) {
      uint d = (uint)dst[base + k];
      atomicAdd(&cnt[(d * NB) / (uint)nrows], 1u);
    }
    __syncthreads();
    uint myc = cnt[tid];
    // phase 2a: reserve global space per bucket
    uint gb = atomicAdd((uint*)&bucketCur[tid], myc);
    // phase 2b: exclusive scan of cnt across 256 threads (wave scan + wave offsets)
    uint v = myc;
#pragma unroll
    for (int off = 1; off < 64; off <<= 1) {
      uint u = __shfl_up(v, off, 64);
      if ((tid & 63) >= off) v += u;
    }
    if ((tid & 63) == 63) gbase[tid >> 6] = v;  // gbase as temp wave-sums
    __syncthreads();
    uint add = 0;
#pragma unroll
    for (int wvi = 0; wvi < 4; ++wvi) add += (wvi < (tid >> 6)) ? gbase[wvi] : 0;
    uint excl = add + v - myc;
    __syncthreads();
    cnt[tid] = excl;   // local offset
    gbase[tid] = gb;   // global base
    cur[tid] = 0;
    __syncthreads();
    // phase 3: place into LDS staging grouped by bucket
    for (int k = tid; k < cntE; k += 256) {
      uint d = (uint)dst[base + k];
      uint s = (uint)src[base + k];
      uint b = (d * NB) / (uint)nrows;
      uint li = atomicAdd(&cur[b], 1u);
      stag[cnt[b] + li] = (d << 16) | s;
    }
    __syncthreads();
    // phase 4: flush runs (contiguous per bucket) to global pairs
    int wv = tid >> 6, ln = tid & 63;
    for (int b = wv; b < 256; b += 4) {
      uint c = cur[b], o = cnt[b], g = gbase[b];
      for (uint k2 = (uint)ln; k2 < c; k2 += 64) pairs[g + k2] = stag[o + k2];
    }
    __syncthreads();
  }
}

// ---------------- pass B: per-bucket CSR segment build in LDS ----------------

__global__ __launch_bounds__(256) void k_csrb(
    const uint* __restrict__ pairs, const int* __restrict__ bucketBase,
    const int* __restrict__ rowoff, const int* __restrict__ deg,
    int* __restrict__ cursor, ushort* __restrict__ csr, int n, int ecnt) {
  __shared__ ushort seg[SEGCAP];
  __shared__ int curs[256];
  int b = blockIdx.x;
  int tid = threadIdx.x;
  int d0 = (b * n + NB - 1) / NB;
  int d1 = ((b + 1) * n + NB - 1) / NB;
  int segbase = rowoff[d0];
  int seglen = rowoff[d1] - segbase;
  int pbase = bucketBase[b];
  int pend = (b == NB - 1) ? ecnt : bucketBase[b + 1];
  if (seglen <= SEGCAP) {
    for (int dl = tid; dl < d1 - d0; dl += 256) curs[dl] = rowoff[d0 + dl] - segbase;
    __syncthreads();
    for (int p = pbase + tid; p < pend; p += 256) {
      uint pr = pairs[p];
      int pos = atomicAdd(&curs[(int)(pr >> 16) - d0], 1);
      seg[pos] = (ushort)(pr & 0xFFFFu);
    }
    __syncthreads();
    for (int dl = tid; dl < d1 - d0; dl += 256) {
      int e0 = curs[dl], e1 = rowoff[d0 + dl + 1] - segbase;
      for (int k = e0; k < e1; ++k) seg[k] = (ushort)n;  // pad -> zero row
    }
    __syncthreads();
    uint4* outp4 = (uint4*)(csr + segbase);
    const uint4* sp = (const uint4*)seg;
    int nq = seglen >> 3;
    for (int k = tid; k < nq; k += 256) outp4[k] = sp[k];
  } else {
    // fallback (extreme skew): direct global placement, correctness only
    for (int p = pbase + tid; p < pend; p += 256) {
      uint pr = pairs[p];
      int pos = atomicAdd(&cursor[pr >> 16], 1);
      csr[pos] = (ushort)(pr & 0xFFFFu);
    }
    __syncthreads();
    for (int dl = tid; dl < d1 - d0; dl += 256) {
      int d = d0 + dl;
      for (int k = rowoff[d] + deg[d]; k < rowoff[d + 1]; ++k) csr[k] = (ushort)n;
    }
  }
}

// ---------------- GEMM2: bf16 A @ f32 B, dinv-from-deg epilogue -> bf16 ---------------

__global__ __launch_bounds__(256) void k_gemmb(const ushort* __restrict__ A,
                                               const float* __restrict__ B,
                                               const int* __restrict__ deg,
                                               ushort* __restrict__ C, int nrows) {
  __shared__ float Bs[DD * 64];
  int tid = threadIdx.x;
  int tx = tid & 15, ty = tid >> 4;
  int rowbase = (blockIdx.x >> 1) * 128;
  int c0 = (blockIdx.x & 1) * 64;
  {
    int kk = tid >> 4;
    int cc = (tid & 15) * 4;
#pragma unroll
    for (int p = 0; p < 8; ++p) {
      int k = p * 16 + kk;
      float4 bv = *reinterpret_cast<const float4*>(&B[k * DD + c0 + cc]);
      *reinterpret_cast<float4*>(&Bs[k * 64 + cc]) = bv;
    }
  }
  __syncthreads();
  float acc[8][4];
#pragma unroll
  for (int i = 0; i < 8; ++i)
#pragma unroll
    for (int j = 0; j < 4; ++j) acc[i][j] = 0.f;
  int rl[8];
#pragma unroll
  for (int i = 0; i < 8; ++i) {
    int r = rowbase + ty * 8 + i;
    rl[i] = (r < nrows) ? r : (nrows - 1);
  }
  const uint4* A16 = reinterpret_cast<const uint4*>(A);
  for (int kq = 0; kq < 16; ++kq) {
    uint4 av[8];
#pragma unroll
    for (int i = 0; i < 8; ++i) av[i] = A16[(size_t)rl[i] * 16 + kq];
#pragma unroll
    for (int kk = 0; kk < 8; ++kk) {
      float4 bv = *reinterpret_cast<const float4*>(&Bs[(kq * 8 + kk) * 64 + tx * 4]);
#pragma unroll
      for (int i = 0; i < 8; ++i) {
        uint wq = (kk < 2) ? av[i].x : (kk < 4) ? av[i].y : (kk < 6) ? av[i].z : av[i].w;
        float a = (kk & 1) ? bfhi(wq) : bflo(wq);
        acc[i][0] = fmaf(a, bv.x, acc[i][0]);
        acc[i][1] = fmaf(a, bv.y, acc[i][1]);
        acc[i][2] = fmaf(a, bv.z, acc[i][2]);
        acc[i][3] = fmaf(a, bv.w, acc[i][3]);
      }
    }
  }
  int cbase = c0 + tx * 4;
#pragma unroll
  for (int i = 0; i < 8; ++i) {
    int r = rowbase + ty * 8 + i;
    if (r < nrows) {
      float dv = rsqrtf((float)deg[r] + 2.0f);
      ushort4 o;
      o.x = f2bf(acc[i][0] * dv); o.y = f2bf(acc[i][1] * dv);
      o.z = f2bf(acc[i][2] * dv); o.w = f2bf(acc[i][3] * dv);
      *reinterpret_cast<ushort4*>(&C[(size_t)r * DD + cbase]) = o;
    }
  }
}

// ---------------- edge accumulate: unweighted gather-sum, u16 CSR ----------------

static __device__ __forceinline__ void edge_accum(
    const uint* __restrict__ xw32, const ushort* __restrict__ csr,
    int start, int cnt, uint lane, float& acc0, float& acc1) {
  const uint4* cs = (const uint4*)(csr + __builtin_amdgcn_readfirstlane(start));
  int rem = __builtin_amdgcn_readfirstlane(cnt);
  uint4 c;
  if (rem >= 8) c = *cs++;
  while (rem >= 16) {
    uint v[8];
    v[0] = xw32[((c.x & 0xFFFFu) << 6) + lane];
    v[1] = xw32[((c.x >> 16) << 6) + lane];
    v[2] = xw32[((c.y & 0xFFFFu) << 6) + lane];
    v[3] = xw32[((c.y >> 16) << 6) + lane];
    v[4] = xw32[((c.z & 0xFFFFu) << 6) + lane];
    v[5] = xw32[((c.z >> 16) << 6) + lane];
    v[6] = xw32[((c.w & 0xFFFFu) << 6) + lane];
    v[7] = xw32[((c.w >> 16) << 6) + lane];
    uint4 cn = *cs++;
#pragma unroll
    for (int j = 0; j < 8; ++j) {
      acc0 += bflo(v[j]);
      acc1 += bfhi(v[j]);
    }
    c = cn; rem -= 8;
  }
  if (rem >= 8) {
    uint v[8];
    v[0] = xw32[((c.x & 0xFFFFu) << 6) + lane];
    v[1] = xw32[((c.x >> 16) << 6) + lane];
    v[2] = xw32[((c.y & 0xFFFFu) << 6) + lane];
    v[3] = xw32[((c.y >> 16) << 6) + lane];
    v[4] = xw32[((c.z & 0xFFFFu) << 6) + lane];
    v[5] = xw32[((c.z >> 16) << 6) + lane];
    v[6] = xw32[((c.w & 0xFFFFu) << 6) + lane];
    v[7] = xw32[((c.w >> 16) << 6) + lane];
#pragma unroll
    for (int j = 0; j < 8; ++j) {
      acc0 += bflo(v[j]);
      acc1 += bfhi(v[j]);
    }
  }
}

// ---------------- agg1 ----------------

__global__ __launch_bounds__(256) void k_agg1(
    const ushort* __restrict__ xwd, const ushort* __restrict__ csr,
    const int* __restrict__ rowoff, const int* __restrict__ deg,
    const float* __restrict__ bias, const float* __restrict__ gam,
    const float* __restrict__ bet, uint* __restrict__ outp, int n) {
  int wv = threadIdx.x >> 6, lane = threadIdx.x & 63;
  int i = blockIdx.x * 4 + wv;
  if (i >= n) return;
  int start = rowoff[i], cnt = rowoff[i + 1] - start;
  float di = rsqrtf((float)deg[i] + 2.0f);
  const uint* xw32 = (const uint*)xwd;
  float acc0 = 0.f, acc1 = 0.f;
  edge_accum(xw32, csr, start, cnt, (uint)lane, acc0, acc1);
  uint su = xw32[((uint)i << 6) + lane];
  float2 bv = ((const float2*)bias)[lane];
  float c0v = fmaf(di, acc0 + 2.f * bflo(su), bv.x);
  float c1v = fmaf(di, acc1 + 2.f * bfhi(su), bv.y);
  float s = c0v + c1v;
#pragma unroll
  for (int off = 32; off > 0; off >>= 1) s += __shfl_xor(s, off);
  float mu = s * (1.f / DD);
  float c0 = c0v - mu, c1 = c1v - mu;
  float q = c0 * c0 + c1 * c1;
#pragma unroll
  for (int off = 32; off > 0; off >>= 1) q += __shfl_xor(q, off);
  float rstd = rsqrtf(q * (1.f / DD) + EPSV);
  float2 gv = ((const float2*)gam)[lane];
  float2 tv = ((const float2*)bet)[lane];
  float h0 = fmaxf(fmaf(c0 * rstd, gv.x, tv.x), 0.f);
  float h1 = fmaxf(fmaf(c1 * rstd, gv.y, tv.y), 0.f);
  uint packed = (uint)f2bf(h0) | ((uint)f2bf(h1) << 16);
  __builtin_nontemporal_store(packed, &outp[((uint)i << 6) + lane]);
}

// ---------------- agg2 ----------------

__global__ __launch_bounds__(256) void k_agg2(
    const ushort* __restrict__ xwd, const ushort* __restrict__ csr,
    const int* __restrict__ rowoff, const int* __restrict__ deg,
    const float* __restrict__ bias, const float* __restrict__ gam,
    const float* __restrict__ bet, const float* __restrict__ Ws,
    const float* __restrict__ bs, const float* __restrict__ We,
    const float* __restrict__ be, const float* __restrict__ xin,
    float* __restrict__ outp, int n) {
  int wv = threadIdx.x >> 6, lane = threadIdx.x & 63;
  int i = blockIdx.x * 4 + wv;
  if (i >= n) return;
  int start = rowoff[i], cnt = rowoff[i + 1] - start;
  float di = rsqrtf((float)deg[i] + 2.0f);
  const uint* xw32 = (const uint*)xwd;
  float acc0 = 0.f, acc1 = 0.f;
  edge_accum(xw32, csr, start, cnt, (uint)lane, acc0, acc1);
  uint su = xw32[((uint)i << 6) + lane];
  float2 bv = ((const float2*)bias)[lane];
  float c0v = fmaf(di, acc0 + 2.f * bflo(su), bv.x);
  float c1v = fmaf(di, acc1 + 2.f * bfhi(su), bv.y);
  float s = c0v + c1v;
#pragma unroll
  for (int off = 32; off > 0; off >>= 1) s += __shfl_xor(s, off);
  float mu = s * (1.f / DD);
  float c0 = c0v - mu, c1 = c1v - mu;
  float q = c0 * c0 + c1 * c1;
#pragma unroll
  for (int off = 32; off > 0; off >>= 1) q += __shfl_xor(q, off);
  float rstd = rsqrtf(q * (1.f / DD) + EPSV);
  float2 gv = ((const float2*)gam)[lane];
  float2 tv = ((const float2*)bet)[lane];
  float h0 = fmaf(c0 * rstd, gv.x, tv.x);
  float h1 = fmaf(c1 * rstd, gv.y, tv.y);
  float pj[HH];
  const float* wr0 = &Ws[(2 * lane) * HH];
  const float* wr1 = &Ws[(2 * lane + 1) * HH];
#pragma unroll
  for (int j = 0; j < HH; ++j) pj[j] = h0 * wr0[j] + h1 * wr1[j];
#pragma unroll
  for (int off = 32; off > 0; off >>= 1) {
#pragma unroll
    for (int j = 0; j < HH; ++j) pj[j] += __shfl_xor(pj[j], off);
  }
  float2 bev = ((const float2*)be)[lane];
  float wacc0 = bev.x, wacc1 = bev.y;
#pragma unroll
  for (int j = 0; j < HH; ++j) {
    float sj = fmaxf(pj[j] + bs[j], 0.f);
    float2 wev = ((const float2*)(We + j * DD))[lane];
    wacc0 = fmaf(sj, wev.x, wacc0);
    wacc1 = fmaf(sj, wev.y, wacc1);
  }
  float w0 = 1.f / (1.f + __expf(-wacc0));
  float w1 = 1.f / (1.f + __expf(-wacc1));
  float2 xr = ((const float2*)(xin + (size_t)i * DD))[lane];
  float2 o;
  o.x = fmaxf(fmaf(h0, w0, xr.x), 0.f);
  o.y = fmaxf(fmaf(h1, w1, xr.y), 0.f);
  ((float2*)(outp + (size_t)i * DD))[lane] = o;
}

// ---------------- launcher ----------------

extern "C" void kernel_launch(void* const* d_in, const int* in_sizes, int n_in,
                              void* d_out, int out_size, void* d_ws, size_t ws_size,
                              hipStream_t stream) {
  const float* x   = (const float*)d_in[0];
  const int*   ei  = (const int*)d_in[1];
  const float* W1  = (const float*)d_in[2];
  const float* b1  = (const float*)d_in[3];
  const float* g1  = (const float*)d_in[4];
  const float* be1 = (const float*)d_in[5];
  const float* W2  = (const float*)d_in[6];
  const float* b2  = (const float*)d_in[7];
  const float* g2  = (const float*)d_in[8];
  const float* be2 = (const float*)d_in[9];
  const float* Ws  = (const float*)d_in[10];
  const float* bs  = (const float*)d_in[11];
  const float* We  = (const float*)d_in[12];
  const float* bee = (const float*)d_in[13];
  float* outp = (float*)d_out;

  int n    = in_sizes[0] / DD;
  int ecnt = in_sizes[1] / 2;
  const int* src = ei;
  const int* dst = ei + ecnt;

  size_t maxent = (size_t)ecnt + 8 * (size_t)n + 64;

  char* w = (char*)d_ws;
  ushort* xwd    = (ushort*)w; w += (size_t)(n + 1) * DD * 2;  // row n = zero row
  uint*   h1     = (uint*)w;   w += (size_t)n * DD * 2;        // bf16 packed
  int*    deg    = (int*)w;    w += (size_t)n * 4;
  int*    cursor = (int*)w;    w += (size_t)n * 4;
  int*    rowoff = (int*)w;    w += (size_t)(n + 1) * 4;
  w = (char*)(((size_t)w + 7) & ~(size_t)7);
  u64*    bsum   = (u64*)w;    w += 64 * 8;
  int*    bktB   = (int*)w;    w += NB * 4;
  int*    bktC   = (int*)w;    w += NB * 4;
  w = (char*)(((size_t)w + 15) & ~(size_t)15);
  uint*   pairs  = (uint*)w;   w += ((size_t)ecnt + 64) * 4;
  w = (char*)(((size_t)w + 15) & ~(size_t)15);
  ushort* csr    = (ushort*)w; w += maxent * 2;

  hipMemsetAsync(deg, 0, (size_t)n * 4, stream);
  hipMemsetAsync(xwd + (size_t)n * DD, 0, DD * 2, stream);

  const int TB = 256;
  k_hist<<<2048, TB, 0, stream>>>(dst, deg, ecnt);
  int nb = (n + SCAN_T * SCAN_I - 1) / (SCAN_T * SCAN_I);
  k_scan1<<<nb, SCAN_T, 0, stream>>>(deg, bsum, n);
  k_scan2<<<nb, SCAN_T, 0, stream>>>(deg, bsum, rowoff, cursor, bktB, bktC, n);

  int gblocks = ((n + 127) / 128) * 2;
  int abloks = (ecnt + TILE - 1) / TILE;
  k_gemm1_bucket<<<abloks + gblocks, TB, 0, stream>>>(
      x, W1, deg, xwd, n, src, dst, bktC, pairs, ecnt, abloks, gblocks);
  k_csrb<<<NB, TB, 0, stream>>>(pairs, bktB, rowoff, deg, cursor, csr, n, ecnt);

  int nb4 = (n + 3) / 4;
  k_agg1<<<nb4, TB, 0, stream>>>(xwd, csr, rowoff, deg, b1, g1, be1, h1, n);
  k_gemmb<<<gblocks, TB, 0, stream>>>((const ushort*)h1, W2, deg, xwd, n);
  k_agg2<<<nb4, TB, 0, stream>>>(xwd, csr, rowoff, deg, b2, g2, be2,
                                 Ws, bs, We, bee, x, outp, n);
}

// Round 14
// 310.930 us; speedup vs baseline: 1.4419x; 1.0507x over previous
//
#include <hip/hip_runtime.h>
#include <math.h>

#define DD 128
#define HH 16
#define NB 256      // dst-range buckets
#define TILE 8192   // edges per pass-A tile
#define SEGCAP 24576
#define EPSV 1e-5f

typedef unsigned long long u64;
typedef __attribute__((ext_vector_type(8))) short short8;
typedef __attribute__((ext_vector_type(4))) float f32x4;
union U4S8 { uint4 u; short8 s; };

static __device__ __forceinline__ ushort f2bf(float f) {
  uint u = __float_as_uint(f);
  u += 0x7FFFu + ((u >> 16) & 1u);
  return (ushort)(u >> 16);
}
static __device__ __forceinline__ float bflo(uint u) { return __uint_as_float(u << 16); }
static __device__ __forceinline__ float bfhi(uint u) { return __uint_as_float(u & 0xFFFF0000u); }

// ---------------- degree histogram + x -> bf16 conversion ----------------

__global__ void k_hist_cvt(const int* __restrict__ dst, int* __restrict__ deg, int ecnt,
                           const float2* __restrict__ x2, uint* __restrict__ xb,
                           int ncnt) {
  int stride = gridDim.x * blockDim.x;
  int t0 = blockIdx.x * blockDim.x + threadIdx.x;
  for (int e = t0; e < ecnt; e += stride) atomicAdd(&deg[dst[e]], 1);
  for (int k = t0; k < ncnt; k += stride) {
    float2 v = x2[k];
    xb[k] = (uint)f2bf(v.x) | ((uint)f2bf(v.y) << 16);
  }
}

// ---------------- scans: packed (padded<<32 | raw) ----------------

#define SCAN_T 1024
#define SCAN_I 4

__global__ void k_scan1(const int* __restrict__ deg, u64* __restrict__ bsum, int n) {
  __shared__ u64 sh[SCAN_T];
  int tid = threadIdx.x;
  int base = blockIdx.x * SCAN_T * SCAN_I + tid * SCAN_I;
  u64 s = 0;
#pragma unroll
  for (int j = 0; j < SCAN_I; ++j) {
    int i = base + j;
    if (i < n) {
      int d = deg[i];
      int dp = (d + 7) & ~7;
      s += ((u64)dp << 32) | (u64)(uint)d;
    }
  }
  sh[tid] = s;
  __syncthreads();
  for (int off = SCAN_T / 2; off > 0; off >>= 1) {
    if (tid < off) sh[tid] += sh[tid + off];
    __syncthreads();
  }
  if (tid == 0) bsum[blockIdx.x] = sh[0];
}

__global__ void k_scan2(const int* __restrict__ deg, const u64* __restrict__ bsum,
                        int* __restrict__ rowoff, int* __restrict__ cursor,
                        int* __restrict__ bucketBase, int* __restrict__ bucketCur,
                        int n) {
  __shared__ u64 sh[SCAN_T];
  __shared__ u64 sbase;
  int tid = threadIdx.x;
  int b = blockIdx.x;
  if (tid == 0) { u64 s = 0; for (int j = 0; j < b; ++j) s += bsum[j]; sbase = s; }
  int base = b * SCAN_T * SCAN_I + tid * SCAN_I;
  int d[SCAN_I]; u64 ts = 0;
#pragma unroll
  for (int j = 0; j < SCAN_I; ++j) {
    int i = base + j;
    d[j] = (i < n) ? deg[i] : 0;
    int dp = (d[j] + 7) & ~7;
    ts += ((u64)dp << 32) | (u64)(uint)d[j];
  }
  sh[tid] = ts;
  __syncthreads();
  for (int off = 1; off < SCAN_T; off <<= 1) {
    u64 v = (tid >= off) ? sh[tid - off] : 0;
    __syncthreads();
    sh[tid] += v;
    __syncthreads();
  }
  u64 ex = sbase + sh[tid] - ts;
#pragma unroll
  for (int j = 0; j < SCAN_I; ++j) {
    int i = base + j;
    if (i < n) {
      int ro = (int)(ex >> 32);
      int raw = (int)(ex & 0xFFFFFFFFu);
      rowoff[i] = ro;
      cursor[i] = ro;
      int bq = (int)(((uint)i * NB) / (uint)n);
      if (i == (bq * n + NB - 1) / NB) { bucketBase[bq] = raw; bucketCur[bq] = raw; }
      int dp = (d[j] + 7) & ~7;
      ex += ((u64)dp << 32) | (u64)(uint)d[j];
      if (i == n - 1) rowoff[n] = (int)(ex >> 32);
    }
  }
}

// ---------------- MFMA GEMM body: C_bf16[n,128] = A_bf16[n,128] @ B_f32[128,128] -------
// Wave computes 64 rows x 16 cols as 4 stacked 16x16 tiles; B frags (bf16-converted)
// register-resident. Layouts (guide-verified): A row=lane&15, k=(lane>>4)*8+j;
// B k=(lane>>4)*8+j, col=lane&15; C/D col=lane&15, row=(lane>>4)*4+reg.

static __device__ __forceinline__ void gemm_mfma_body(
    const uint4* __restrict__ A16, const float* __restrict__ B,
    const int* __restrict__ deg, ushort* __restrict__ C, int nrows, int bx) {
  int tid = threadIdx.x;
  int wv = tid >> 6, l = tid & 63;
  int rowbase = (bx >> 1) * 64;
  int c0 = (bx & 1) * 64;
  int colb = c0 + (wv << 4) + (l & 15);
  int kb = (l >> 4) << 3;  // 0,8,16,24
  uint4 bf[4];
#pragma unroll
  for (int ks = 0; ks < 4; ++ks) {
    const float* Bp = B + (size_t)(ks * 32 + kb) * DD + colb;
    float b0 = Bp[0], b1 = Bp[DD], b2 = Bp[2 * DD], b3 = Bp[3 * DD];
    float b4 = Bp[4 * DD], b5 = Bp[5 * DD], b6 = Bp[6 * DD], b7 = Bp[7 * DD];
    bf[ks].x = (uint)f2bf(b0) | ((uint)f2bf(b1) << 16);
    bf[ks].y = (uint)f2bf(b2) | ((uint)f2bf(b3) << 16);
    bf[ks].z = (uint)f2bf(b4) | ((uint)f2bf(b5) << 16);
    bf[ks].w = (uint)f2bf(b6) | ((uint)f2bf(b7) << 16);
  }
#pragma unroll
  for (int rt = 0; rt < 4; ++rt) {
    int r = rowbase + rt * 16 + (l & 15);
    int rc = (r < nrows) ? r : (nrows - 1);
    f32x4 acc = {0.f, 0.f, 0.f, 0.f};
#pragma unroll
    for (int ks = 0; ks < 4; ++ks) {
      U4S8 ua, ub;
      ua.u = A16[(size_t)rc * 16 + (ks << 2) + (l >> 4)];
      ub.u = bf[ks];
      acc = __builtin_amdgcn_mfma_f32_16x16x32_bf16(ua.s, ub.s, acc, 0, 0, 0);
    }
#pragma unroll
    for (int ri = 0; ri < 4; ++ri) {
      int row = rowbase + rt * 16 + ((l >> 4) << 2) + ri;
      if (row < nrows) {
        float dv = rsqrtf((float)deg[row] + 2.0f);
        C[(size_t)row * DD + colb] = f2bf(acc[ri] * dv);
      }
    }
  }
}

// ---------------- GEMM1 (MFMA) fused with pass-A bucket scatter ----------------

__global__ __launch_bounds__(256) void k_gemm1_bucket(
    const uint4* __restrict__ A16, const float* __restrict__ B,
    const int* __restrict__ deg, ushort* __restrict__ C, int nrows,
    const int* __restrict__ src, const int* __restrict__ dst,
    int* __restrict__ bucketCur, uint* __restrict__ pairs, int ecnt,
    int abloks, int gblocks) {
  __shared__ uint smem[8960];  // 35 KB: staging 8192 + cnt 256 + gbase 256 + cur 256
  int bx = blockIdx.x;
  if (bx >= abloks) {
    gemm_mfma_body(A16, B, deg, C, nrows, bx - abloks);
    return;
  }
  uint* stag  = smem;
  uint* cnt   = smem + 8192;
  uint* gbase = smem + 8448;
  uint* cur   = smem + 8704;
  int tid = threadIdx.x;
  int ntiles = (ecnt + TILE - 1) / TILE;
  for (int t = bx; t < ntiles; t += abloks) {
    int base = t * TILE;
    int cntE = min(TILE, ecnt - base);
    cnt[tid] = 0;
    __syncthreads();
    for (int k = tid; k < cntE; k += 256) {
      uint d = (uint)dst[base + k];
      atomicAdd(&cnt[(d * NB) / (uint)nrows], 1u);
    }
    __syncthreads();
    uint myc = cnt[tid];
    uint gb = atomicAdd((uint*)&bucketCur[tid], myc);
    uint v = myc;
#pragma unroll
    for (int off = 1; off < 64; off <<= 1) {
      uint u = __shfl_up(v, off, 64);
      if ((tid & 63) >= off) v += u;
    }
    if ((tid & 63) == 63) gbase[tid >> 6] = v;
    __syncthreads();
    uint add = 0;
#pragma unroll
    for (int wvi = 0; wvi < 4; ++wvi) add += (wvi < (tid >> 6)) ? gbase[wvi] : 0;
    uint excl = add + v - myc;
    __syncthreads();
    cnt[tid] = excl;
    gbase[tid] = gb;
    cur[tid] = 0;
    __syncthreads();
    for (int k = tid; k < cntE; k += 256) {
      uint d = (uint)dst[base + k];
      uint s = (uint)src[base + k];
      uint b = (d * NB) / (uint)nrows;
      uint li = atomicAdd(&cur[b], 1u);
      stag[cnt[b] + li] = (d << 16) | s;
    }
    __syncthreads();
    int wv = tid >> 6, ln = tid & 63;
    for (int b = wv; b < 256; b += 4) {
      uint c = cur[b], o = cnt[b], g = gbase[b];
      for (uint k2 = (uint)ln; k2 < c; k2 += 64) pairs[g + k2] = stag[o + k2];
    }
    __syncthreads();
  }
}

__global__ __launch_bounds__(256) void k_gemmb(
    const uint4* __restrict__ A16, const float* __restrict__ B,
    const int* __restrict__ deg, ushort* __restrict__ C, int nrows) {
  gemm_mfma_body(A16, B, deg, C, nrows, blockIdx.x);
}

// ---------------- pass B: per-bucket CSR segment build in LDS ----------------

__global__ __launch_bounds__(256) void k_csrb(
    const uint* __restrict__ pairs, const int* __restrict__ bucketBase,
    const int* __restrict__ rowoff, const int* __restrict__ deg,
    int* __restrict__ cursor, ushort* __restrict__ csr, int n, int ecnt) {
  __shared__ ushort seg[SEGCAP];
  __shared__ int curs[256];
  int b = blockIdx.x;
  int tid = threadIdx.x;
  int d0 = (b * n + NB - 1) / NB;
  int d1 = ((b + 1) * n + NB - 1) / NB;
  int segbase = rowoff[d0];
  int seglen = rowoff[d1] - segbase;
  int pbase = bucketBase[b];
  int pend = (b == NB - 1) ? ecnt : bucketBase[b + 1];
  if (seglen <= SEGCAP) {
    for (int dl = tid; dl < d1 - d0; dl += 256) curs[dl] = rowoff[d0 + dl] - segbase;
    __syncthreads();
    for (int p = pbase + tid; p < pend; p += 256) {
      uint pr = pairs[p];
      int pos = atomicAdd(&curs[(int)(pr >> 16) - d0], 1);
      seg[pos] = (ushort)(pr & 0xFFFFu);
    }
    __syncthreads();
    for (int dl = tid; dl < d1 - d0; dl += 256) {
      int e0 = curs[dl], e1 = rowoff[d0 + dl + 1] - segbase;
      for (int k = e0; k < e1; ++k) seg[k] = (ushort)n;
    }
    __syncthreads();
    uint4* outp4 = (uint4*)(csr + segbase);
    const uint4* sp = (const uint4*)seg;
    int nq = seglen >> 3;
    for (int k = tid; k < nq; k += 256) outp4[k] = sp[k];
  } else {
    for (int p = pbase + tid; p < pend; p += 256) {
      uint pr = pairs[p];
      int pos = atomicAdd(&cursor[pr >> 16], 1);
      csr[pos] = (ushort)(pr & 0xFFFFu);
    }
    __syncthreads();
    for (int dl = tid; dl < d1 - d0; dl += 256) {
      int d = d0 + dl;
      for (int k = rowoff[d] + deg[d]; k < rowoff[d + 1]; ++k) csr[k] = (ushort)n;
    }
  }
}

// ---------------- edge accumulate: unweighted gather-sum, u16 CSR ----------------

static __device__ __forceinline__ void edge_accum(
    const uint* __restrict__ xw32, const ushort* __restrict__ csr,
    int start, int cnt, uint lane, float& acc0, float& acc1) {
  const uint4* cs = (const uint4*)(csr + __builtin_amdgcn_readfirstlane(start));
  int rem = __builtin_amdgcn_readfirstlane(cnt);
  uint4 c;
  if (rem >= 8) c = *cs++;
  while (rem >= 16) {
    uint v[8];
    v[0] = xw32[((c.x & 0xFFFFu) << 6) + lane];
    v[1] = xw32[((c.x >> 16) << 6) + lane];
    v[2] = xw32[((c.y & 0xFFFFu) << 6) + lane];
    v[3] = xw32[((c.y >> 16) << 6) + lane];
    v[4] = xw32[((c.z & 0xFFFFu) << 6) + lane];
    v[5] = xw32[((c.z >> 16) << 6) + lane];
    v[6] = xw32[((c.w & 0xFFFFu) << 6) + lane];
    v[7] = xw32[((c.w >> 16) << 6) + lane];
    uint4 cn = *cs++;
#pragma unroll
    for (int j = 0; j < 8; ++j) {
      acc0 += bflo(v[j]);
      acc1 += bfhi(v[j]);
    }
    c = cn; rem -= 8;
  }
  if (rem >= 8) {
    uint v[8];
    v[0] = xw32[((c.x & 0xFFFFu) << 6) + lane];
    v[1] = xw32[((c.x >> 16) << 6) + lane];
    v[2] = xw32[((c.y & 0xFFFFu) << 6) + lane];
    v[3] = xw32[((c.y >> 16) << 6) + lane];
    v[4] = xw32[((c.z & 0xFFFFu) << 6) + lane];
    v[5] = xw32[((c.z >> 16) << 6) + lane];
    v[6] = xw32[((c.w & 0xFFFFu) << 6) + lane];
    v[7] = xw32[((c.w >> 16) << 6) + lane];
#pragma unroll
    for (int j = 0; j < 8; ++j) {
      acc0 += bflo(v[j]);
      acc1 += bfhi(v[j]);
    }
  }
}

// ---------------- agg1 ----------------

__global__ __launch_bounds__(256) void k_agg1(
    const ushort* __restrict__ xwd, const ushort* __restrict__ csr,
    const int* __restrict__ rowoff, const int* __restrict__ deg,
    const float* __restrict__ bias, const float* __restrict__ gam,
    const float* __restrict__ bet, uint* __restrict__ outp, int n) {
  int wv = threadIdx.x >> 6, lane = threadIdx.x & 63;
  int i = blockIdx.x * 4 + wv;
  if (i >= n) return;
  int start = rowoff[i], cnt = rowoff[i + 1] - start;
  float di = rsqrtf((float)deg[i] + 2.0f);
  const uint* xw32 = (const uint*)xwd;
  float acc0 = 0.f, acc1 = 0.f;
  edge_accum(xw32, csr, start, cnt, (uint)lane, acc0, acc1);
  uint su = xw32[((uint)i << 6) + lane];
  float2 bv = ((const float2*)bias)[lane];
  float c0v = fmaf(di, acc0 + 2.f * bflo(su), bv.x);
  float c1v = fmaf(di, acc1 + 2.f * bfhi(su), bv.y);
  float s = c0v + c1v;
#pragma unroll
  for (int off = 32; off > 0; off >>= 1) s += __shfl_xor(s, off);
  float mu = s * (1.f / DD);
  float c0 = c0v - mu, c1 = c1v - mu;
  float q = c0 * c0 + c1 * c1;
#pragma unroll
  for (int off = 32; off > 0; off >>= 1) q += __shfl_xor(q, off);
  float rstd = rsqrtf(q * (1.f / DD) + EPSV);
  float2 gv = ((const float2*)gam)[lane];
  float2 tv = ((const float2*)bet)[lane];
  float h0 = fmaxf(fmaf(c0 * rstd, gv.x, tv.x), 0.f);
  float h1 = fmaxf(fmaf(c1 * rstd, gv.y, tv.y), 0.f);
  uint packed = (uint)f2bf(h0) | ((uint)f2bf(h1) << 16);
  __builtin_nontemporal_store(packed, &outp[((uint)i << 6) + lane]);
}

// ---------------- agg2 ----------------

__global__ __launch_bounds__(256) void k_agg2(
    const ushort* __restrict__ xwd, const ushort* __restrict__ csr,
    const int* __restrict__ rowoff, const int* __restrict__ deg,
    const float* __restrict__ bias, const float* __restrict__ gam,
    const float* __restrict__ bet, const float* __restrict__ Ws,
    const float* __restrict__ bs, const float* __restrict__ We,
    const float* __restrict__ be, const float* __restrict__ xin,
    float* __restrict__ outp, int n) {
  int wv = threadIdx.x >> 6, lane = threadIdx.x & 63;
  int i = blockIdx.x * 4 + wv;
  if (i >= n) return;
  int start = rowoff[i], cnt = rowoff[i + 1] - start;
  float di = rsqrtf((float)deg[i] + 2.0f);
  const uint* xw32 = (const uint*)xwd;
  float acc0 = 0.f, acc1 = 0.f;
  edge_accum(xw32, csr, start, cnt, (uint)lane, acc0, acc1);
  uint su = xw32[((uint)i << 6) + lane];
  float2 bv = ((const float2*)bias)[lane];
  float c0v = fmaf(di, acc0 + 2.f * bflo(su), bv.x);
  float c1v = fmaf(di, acc1 + 2.f * bfhi(su), bv.y);
  float s = c0v + c1v;
#pragma unroll
  for (int off = 32; off > 0; off >>= 1) s += __shfl_xor(s, off);
  float mu = s * (1.f / DD);
  float c0 = c0v - mu, c1 = c1v - mu;
  float q = c0 * c0 + c1 * c1;
#pragma unroll
  for (int off = 32; off > 0; off >>= 1) q += __shfl_xor(q, off);
  float rstd = rsqrtf(q * (1.f / DD) + EPSV);
  float2 gv = ((const float2*)gam)[lane];
  float2 tv = ((const float2*)bet)[lane];
  float h0 = fmaf(c0 * rstd, gv.x, tv.x);
  float h1 = fmaf(c1 * rstd, gv.y, tv.y);
  float pj[HH];
  const float* wr0 = &Ws[(2 * lane) * HH];
  const float* wr1 = &Ws[(2 * lane + 1) * HH];
#pragma unroll
  for (int j = 0; j < HH; ++j) pj[j] = h0 * wr0[j] + h1 * wr1[j];
#pragma unroll
  for (int off = 32; off > 0; off >>= 1) {
#pragma unroll
    for (int j = 0; j < HH; ++j) pj[j] += __shfl_xor(pj[j], off);
  }
  float2 bev = ((const float2*)be)[lane];
  float wacc0 = bev.x, wacc1 = bev.y;
#pragma unroll
  for (int j = 0; j < HH; ++j) {
    float sj = fmaxf(pj[j] + bs[j], 0.f);
    float2 wev = ((const float2*)(We + j * DD))[lane];
    wacc0 = fmaf(sj, wev.x, wacc0);
    wacc1 = fmaf(sj, wev.y, wacc1);
  }
  float w0 = 1.f / (1.f + __expf(-wacc0));
  float w1 = 1.f / (1.f + __expf(-wacc1));
  float2 xr = ((const float2*)(xin + (size_t)i * DD))[lane];
  float2 o;
  o.x = fmaxf(fmaf(h0, w0, xr.x), 0.f);
  o.y = fmaxf(fmaf(h1, w1, xr.y), 0.f);
  ((float2*)(outp + (size_t)i * DD))[lane] = o;
}

// ---------------- launcher ----------------

extern "C" void kernel_launch(void* const* d_in, const int* in_sizes, int n_in,
                              void* d_out, int out_size, void* d_ws, size_t ws_size,
                              hipStream_t stream) {
  const float* x   = (const float*)d_in[0];
  const int*   ei  = (const int*)d_in[1];
  const float* W1  = (const float*)d_in[2];
  const float* b1  = (const float*)d_in[3];
  const float* g1  = (const float*)d_in[4];
  const float* be1 = (const float*)d_in[5];
  const float* W2  = (const float*)d_in[6];
  const float* b2  = (const float*)d_in[7];
  const float* g2  = (const float*)d_in[8];
  const float* be2 = (const float*)d_in[9];
  const float* Ws  = (const float*)d_in[10];
  const float* bs  = (const float*)d_in[11];
  const float* We  = (const float*)d_in[12];
  const float* bee = (const float*)d_in[13];
  float* outp = (float*)d_out;

  int n    = in_sizes[0] / DD;
  int ecnt = in_sizes[1] / 2;
  const int* src = ei;
  const int* dst = ei + ecnt;

  size_t maxent = (size_t)ecnt + 8 * (size_t)n + 64;

  char* w = (char*)d_ws;
  ushort* xwd    = (ushort*)w; w += (size_t)(n + 1) * DD * 2;  // row n = zero row
  uint*   h1     = (uint*)w;   w += (size_t)n * DD * 2;        // bf16 packed
  uint*   xb     = (uint*)w;   w += (size_t)n * DD * 2;        // x as bf16 packed
  int*    deg    = (int*)w;    w += (size_t)n * 4;
  int*    cursor = (int*)w;    w += (size_t)n * 4;
  int*    rowoff = (int*)w;    w += (size_t)(n + 1) * 4;
  w = (char*)(((size_t)w + 7) & ~(size_t)7);
  u64*    bsum   = (u64*)w;    w += 64 * 8;
  int*    bktB   = (int*)w;    w += NB * 4;
  int*    bktC   = (int*)w;    w += NB * 4;
  w = (char*)(((size_t)w + 15) & ~(size_t)15);
  uint*   pairs  = (uint*)w;   w += ((size_t)ecnt + 64) * 4;
  w = (char*)(((size_t)w + 15) & ~(size_t)15);
  ushort* csr    = (ushort*)w; w += maxent * 2;

  hipMemsetAsync(deg, 0, (size_t)n * 4, stream);
  hipMemsetAsync(xwd + (size_t)n * DD, 0, DD * 2, stream);

  const int TB = 256;
  k_hist_cvt<<<2048, TB, 0, stream>>>(dst, deg, ecnt, (const float2*)x, xb, n * 64);
  int nb = (n + SCAN_T * SCAN_I - 1) / (SCAN_T * SCAN_I);
  k_scan1<<<nb, SCAN_T, 0, stream>>>(deg, bsum, n);
  k_scan2<<<nb, SCAN_T, 0, stream>>>(deg, bsum, rowoff, cursor, bktB, bktC, n);

  int gblocks = ((n + 63) / 64) * 2;
  int abloks = (ecnt + TILE - 1) / TILE;
  k_gemm1_bucket<<<abloks + gblocks, TB, 0, stream>>>(
      (const uint4*)xb, W1, deg, xwd, n, src, dst, bktC, pairs, ecnt, abloks, gblocks);
  k_csrb<<<NB, TB, 0, stream>>>(pairs, bktB, rowoff, deg, cursor, csr, n, ecnt);

  int nb4 = (n + 3) / 4;
  k_agg1<<<nb4, TB, 0, stream>>>(xwd, csr, rowoff, deg, b1, g1, be1, h1, n);
  k_gemmb<<<gblocks, TB, 0, stream>>>((const uint4*)h1, W2, deg, xwd, n);
  k_agg2<<<nb4, TB, 0, stream>>>(xwd, csr, rowoff, deg, b2, g2, be2,
                                 Ws, bs, We, bee, x, outp, n);
}

// Round 15
// 306.075 us; speedup vs baseline: 1.4648x; 1.0159x over previous
//
#include <hip/hip_runtime.h>
#include <math.h>

#define DD 128
#define HH 16
#define NB 256      // dst-range buckets
#define TILE 8192   // edges per pass-A tile
#define SEGCAP 24576
#define EPSV 1e-5f

typedef unsigned long long u64;
typedef __attribute__((ext_vector_type(8))) short short8;
typedef __attribute__((ext_vector_type(4))) float f32x4;
union U4S8 { uint4 u; short8 s; };

static __device__ __forceinline__ ushort f2bf(float f) {
  uint u = __float_as_uint(f);
  u += 0x7FFFu + ((u >> 16) & 1u);
  return (ushort)(u >> 16);
}
static __device__ __forceinline__ uint pk(float a, float b) {
  return (uint)f2bf(a) | ((uint)f2bf(b) << 16);
}
static __device__ __forceinline__ float bflo(uint u) { return __uint_as_float(u << 16); }
static __device__ __forceinline__ float bfhi(uint u) { return __uint_as_float(u & 0xFFFF0000u); }

// ---------------- degree histogram + W1/W2 -> MFMA B-fragment layout ----------------
// Wf layout: [8 coltile][4 kstep][64 lane] uint4; component jj packs bf16 of
// W[k=ks*32+(l>>4)*8+2jj][col=ct*16+(l&15)] and k+1.

__global__ void k_hist_prep(const int* __restrict__ dst, int* __restrict__ deg, int ecnt,
                            const float* __restrict__ W1, const float* __restrict__ W2,
                            uint4* __restrict__ W1f, uint4* __restrict__ W2f) {
  int stride = gridDim.x * blockDim.x;
  int t0 = blockIdx.x * blockDim.x + threadIdx.x;
  for (int e = t0; e < ecnt; e += stride) atomicAdd(&deg[dst[e]], 1);
  for (int t = t0; t < 4096; t += stride) {
    int m = t >> 11;
    int r = t & 2047;
    int ct = r >> 8, ks = (r >> 6) & 3, l = r & 63;
    int col = ct * 16 + (l & 15);
    int kb = ks * 32 + ((l >> 4) << 3);
    const float* W = m ? W2 : W1;
    uint4 v;
    v.x = pk(W[(kb + 0) * DD + col], W[(kb + 1) * DD + col]);
    v.y = pk(W[(kb + 2) * DD + col], W[(kb + 3) * DD + col]);
    v.z = pk(W[(kb + 4) * DD + col], W[(kb + 5) * DD + col]);
    v.w = pk(W[(kb + 6) * DD + col], W[(kb + 7) * DD + col]);
    (m ? W2f : W1f)[(ct * 4 + ks) * 64 + l] = v;
  }
}

// ---------------- scans: packed (padded<<32 | raw) ----------------

#define SCAN_T 1024
#define SCAN_I 4

__global__ void k_scan1(const int* __restrict__ deg, u64* __restrict__ bsum, int n) {
  __shared__ u64 sh[SCAN_T];
  int tid = threadIdx.x;
  int base = blockIdx.x * SCAN_T * SCAN_I + tid * SCAN_I;
  u64 s = 0;
#pragma unroll
  for (int j = 0; j < SCAN_I; ++j) {
    int i = base + j;
    if (i < n) {
      int d = deg[i];
      int dp = (d + 7) & ~7;
      s += ((u64)dp << 32) | (u64)(uint)d;
    }
  }
  sh[tid] = s;
  __syncthreads();
  for (int off = SCAN_T / 2; off > 0; off >>= 1) {
    if (tid < off) sh[tid] += sh[tid + off];
    __syncthreads();
  }
  if (tid == 0) bsum[blockIdx.x] = sh[0];
}

__global__ void k_scan2(const int* __restrict__ deg, const u64* __restrict__ bsum,
                        int* __restrict__ rowoff, int* __restrict__ cursor,
                        int* __restrict__ bucketBase, int* __restrict__ bucketCur,
                        int n) {
  __shared__ u64 sh[SCAN_T];
  __shared__ u64 sbase;
  int tid = threadIdx.x;
  int b = blockIdx.x;
  if (tid == 0) { u64 s = 0; for (int j = 0; j < b; ++j) s += bsum[j]; sbase = s; }
  int base = b * SCAN_T * SCAN_I + tid * SCAN_I;
  int d[SCAN_I]; u64 ts = 0;
#pragma unroll
  for (int j = 0; j < SCAN_I; ++j) {
    int i = base + j;
    d[j] = (i < n) ? deg[i] : 0;
    int dp = (d[j] + 7) & ~7;
    ts += ((u64)dp << 32) | (u64)(uint)d[j];
  }
  sh[tid] = ts;
  __syncthreads();
  for (int off = 1; off < SCAN_T; off <<= 1) {
    u64 v = (tid >= off) ? sh[tid - off] : 0;
    __syncthreads();
    sh[tid] += v;
    __syncthreads();
  }
  u64 ex = sbase + sh[tid] - ts;
#pragma unroll
  for (int j = 0; j < SCAN_I; ++j) {
    int i = base + j;
    if (i < n) {
      int ro = (int)(ex >> 32);
      int raw = (int)(ex & 0xFFFFFFFFu);
      rowoff[i] = ro;
      cursor[i] = ro;
      int bq = (int)(((uint)i * NB) / (uint)n);
      if (i == (bq * n + NB - 1) / NB) { bucketBase[bq] = raw; bucketCur[bq] = raw; }
      int dp = (d[j] + 7) & ~7;
      ex += ((u64)dp << 32) | (u64)(uint)d[j];
      if (i == n - 1) rowoff[n] = (int)(ex >> 32);
    }
  }
}

// ---------------- MFMA GEMM1 body: xwd = bf16(dinv * (x @ W1)), A from fp32 x ----------

static __device__ __forceinline__ void gemm_mfma_x(
    const float* __restrict__ x, const uint4* __restrict__ W1f,
    const int* __restrict__ deg, ushort* __restrict__ C, int nrows, int bx) {
  int tid = threadIdx.x;
  int wv = tid >> 6, l = tid & 63;
  int rowbase = (bx >> 1) * 64;
  int ctg = (bx & 1) * 4 + wv;
  int colb = ctg * 16 + (l & 15);
  uint4 bf[4];
#pragma unroll
  for (int ks = 0; ks < 4; ++ks) bf[ks] = W1f[(ctg * 4 + ks) * 64 + l];
#pragma unroll
  for (int rt = 0; rt < 4; ++rt) {
    int r = rowbase + rt * 16 + (l & 15);
    int rc = (r < nrows) ? r : (nrows - 1);
    f32x4 acc = {0.f, 0.f, 0.f, 0.f};
#pragma unroll
    for (int ks = 0; ks < 4; ++ks) {
      const float4* xp = (const float4*)(x + (size_t)rc * DD + ks * 32 + ((l >> 4) << 3));
      float4 a0 = xp[0], a1 = xp[1];
      U4S8 ua, ub;
      ua.u.x = pk(a0.x, a0.y);
      ua.u.y = pk(a0.z, a0.w);
      ua.u.z = pk(a1.x, a1.y);
      ua.u.w = pk(a1.z, a1.w);
      ub.u = bf[ks];
      acc = __builtin_amdgcn_mfma_f32_16x16x32_bf16(ua.s, ub.s, acc, 0, 0, 0);
    }
#pragma unroll
    for (int ri = 0; ri < 4; ++ri) {
      int row = rowbase + rt * 16 + ((l >> 4) << 2) + ri;
      if (row < nrows) {
        float dv = rsqrtf((float)deg[row] + 2.0f);
        C[(size_t)row * DD + colb] = f2bf(acc[ri] * dv);
      }
    }
  }
}

// ---------------- GEMM1 (MFMA) fused with pass-A bucket scatter ----------------

__global__ __launch_bounds__(256) void k_gemm1_bucket(
    const float* __restrict__ x, const uint4* __restrict__ W1f,
    const int* __restrict__ deg, ushort* __restrict__ C, int nrows,
    const int* __restrict__ src, const int* __restrict__ dst,
    int* __restrict__ bucketCur, uint* __restrict__ pairs, int ecnt,
    int abloks, int gblocks) {
  __shared__ uint smem[8960];
  int bx = blockIdx.x;
  if (bx >= abloks) {
    gemm_mfma_x(x, W1f, deg, C, nrows, bx - abloks);
    return;
  }
  uint* stag  = smem;
  uint* cnt   = smem + 8192;
  uint* gbase = smem + 8448;
  uint* cur   = smem + 8704;
  int tid = threadIdx.x;
  int ntiles = (ecnt + TILE - 1) / TILE;
  for (int t = bx; t < ntiles; t += abloks) {
    int base = t * TILE;
    int cntE = min(TILE, ecnt - base);
    cnt[tid] = 0;
    __syncthreads();
    for (int k = tid; k < cntE; k += 256) {
      uint d = (uint)dst[base + k];
      atomicAdd(&cnt[(d * NB) / (uint)nrows], 1u);
    }
    __syncthreads();
    uint myc = cnt[tid];
    uint gb = atomicAdd((uint*)&bucketCur[tid], myc);
    uint v = myc;
#pragma unroll
    for (int off = 1; off < 64; off <<= 1) {
      uint u = __shfl_up(v, off, 64);
      if ((tid & 63) >= off) v += u;
    }
    if ((tid & 63) == 63) gbase[tid >> 6] = v;
    __syncthreads();
    uint add = 0;
#pragma unroll
    for (int wvi = 0; wvi < 4; ++wvi) add += (wvi < (tid >> 6)) ? gbase[wvi] : 0;
    uint excl = add + v - myc;
    __syncthreads();
    cnt[tid] = excl;
    gbase[tid] = gb;
    cur[tid] = 0;
    __syncthreads();
    for (int k = tid; k < cntE; k += 256) {
      uint d = (uint)dst[base + k];
      uint s = (uint)src[base + k];
      uint b = (d * NB) / (uint)nrows;
      uint li = atomicAdd(&cur[b], 1u);
      stag[cnt[b] + li] = (d << 16) | s;
    }
    __syncthreads();
    int wv = tid >> 6, ln = tid & 63;
    for (int b = wv; b < 256; b += 4) {
      uint c = cur[b], o = cnt[b], g = gbase[b];
      for (uint k2 = (uint)ln; k2 < c; k2 += 64) pairs[g + k2] = stag[o + k2];
    }
    __syncthreads();
  }
}

// ---------------- pass B: per-bucket CSR segment build in LDS ----------------

__global__ __launch_bounds__(256) void k_csrb(
    const uint* __restrict__ pairs, const int* __restrict__ bucketBase,
    const int* __restrict__ rowoff, const int* __restrict__ deg,
    int* __restrict__ cursor, ushort* __restrict__ csr, int n, int ecnt) {
  __shared__ ushort seg[SEGCAP];
  __shared__ int curs[256];
  int b = blockIdx.x;
  int tid = threadIdx.x;
  int d0 = (b * n + NB - 1) / NB;
  int d1 = ((b + 1) * n + NB - 1) / NB;
  int segbase = rowoff[d0];
  int seglen = rowoff[d1] - segbase;
  int pbase = bucketBase[b];
  int pend = (b == NB - 1) ? ecnt : bucketBase[b + 1];
  if (seglen <= SEGCAP) {
    for (int dl = tid; dl < d1 - d0; dl += 256) curs[dl] = rowoff[d0 + dl] - segbase;
    __syncthreads();
    for (int p = pbase + tid; p < pend; p += 256) {
      uint pr = pairs[p];
      int pos = atomicAdd(&curs[(int)(pr >> 16) - d0], 1);
      seg[pos] = (ushort)(pr & 0xFFFFu);
    }
    __syncthreads();
    for (int dl = tid; dl < d1 - d0; dl += 256) {
      int e0 = curs[dl], e1 = rowoff[d0 + dl + 1] - segbase;
      for (int k = e0; k < e1; ++k) seg[k] = (ushort)n;
    }
    __syncthreads();
    uint4* outp4 = (uint4*)(csr + segbase);
    const uint4* sp = (const uint4*)seg;
    int nq = seglen >> 3;
    for (int k = tid; k < nq; k += 256) outp4[k] = sp[k];
  } else {
    for (int p = pbase + tid; p < pend; p += 256) {
      uint pr = pairs[p];
      int pos = atomicAdd(&cursor[pr >> 16], 1);
      csr[pos] = (ushort)(pr & 0xFFFFu);
    }
    __syncthreads();
    for (int dl = tid; dl < d1 - d0; dl += 256) {
      int d = d0 + dl;
      for (int k = rowoff[d] + deg[d]; k < rowoff[d + 1]; ++k) csr[k] = (ushort)n;
    }
  }
}

// ---------------- edge accumulate: unweighted gather-sum, u16 CSR ----------------

static __device__ __forceinline__ void edge_accum(
    const uint* __restrict__ xw32, const ushort* __restrict__ csr,
    int start, int cnt, uint lane, float& acc0, float& acc1) {
  const uint4* cs = (const uint4*)(csr + __builtin_amdgcn_readfirstlane(start));
  int rem = __builtin_amdgcn_readfirstlane(cnt);
  uint4 c;
  if (rem >= 8) c = *cs++;
  while (rem >= 16) {
    uint v[8];
    v[0] = xw32[((c.x & 0xFFFFu) << 6) + lane];
    v[1] = xw32[((c.x >> 16) << 6) + lane];
    v[2] = xw32[((c.y & 0xFFFFu) << 6) + lane];
    v[3] = xw32[((c.y >> 16) << 6) + lane];
    v[4] = xw32[((c.z & 0xFFFFu) << 6) + lane];
    v[5] = xw32[((c.z >> 16) << 6) + lane];
    v[6] = xw32[((c.w & 0xFFFFu) << 6) + lane];
    v[7] = xw32[((c.w >> 16) << 6) + lane];
    uint4 cn = *cs++;
#pragma unroll
    for (int j = 0; j < 8; ++j) {
      acc0 += bflo(v[j]);
      acc1 += bfhi(v[j]);
    }
    c = cn; rem -= 8;
  }
  if (rem >= 8) {
    uint v[8];
    v[0] = xw32[((c.x & 0xFFFFu) << 6) + lane];
    v[1] = xw32[((c.x >> 16) << 6) + lane];
    v[2] = xw32[((c.y & 0xFFFFu) << 6) + lane];
    v[3] = xw32[((c.y >> 16) << 6) + lane];
    v[4] = xw32[((c.z & 0xFFFFu) << 6) + lane];
    v[5] = xw32[((c.z >> 16) << 6) + lane];
    v[6] = xw32[((c.w & 0xFFFFu) << 6) + lane];
    v[7] = xw32[((c.w >> 16) << 6) + lane];
#pragma unroll
    for (int j = 0; j < 8; ++j) {
      acc0 += bflo(v[j]);
      acc1 += bfhi(v[j]);
    }
  }
}

// ---------------- agg1 fused with GEMM2: gather+LN+ReLU -> h (LDS) -> MFMA @ W2 -------
// Block = 4 waves = 4 nodes. h rows staged in LDS [16][64] uints (slots 4-15 garbage,
// their C rows never stored). Wave w computes coltiles {2w, 2w+1}; C rows 0-3 = the
// block's 4 nodes, stored scaled by dinv into xwd2.

__global__ __launch_bounds__(256) void k_agg1f(
    const ushort* __restrict__ xwd, const ushort* __restrict__ csr,
    const int* __restrict__ rowoff, const int* __restrict__ deg,
    const float* __restrict__ bias, const float* __restrict__ gam,
    const float* __restrict__ bet, const uint4* __restrict__ W2f,
    ushort* __restrict__ xwd2, int n) {
  __shared__ uint hls[16 * 64];
  __shared__ float dvs[4];
  int wv = threadIdx.x >> 6, lane = threadIdx.x & 63;
  int i = blockIdx.x * 4 + wv;
  int iv = (i < n) ? i : (n - 1);
  int start = rowoff[iv], cnt = rowoff[iv + 1] - start;
  float di = rsqrtf((float)deg[iv] + 2.0f);
  const uint* xw32 = (const uint*)xwd;
  float acc0 = 0.f, acc1 = 0.f;
  edge_accum(xw32, csr, start, cnt, (uint)lane, acc0, acc1);
  uint su = xw32[((uint)iv << 6) + lane];
  float2 bv = ((const float2*)bias)[lane];
  float c0v = fmaf(di, acc0 + 2.f * bflo(su), bv.x);
  float c1v = fmaf(di, acc1 + 2.f * bfhi(su), bv.y);
  float s = c0v + c1v;
#pragma unroll
  for (int off = 32; off > 0; off >>= 1) s += __shfl_xor(s, off);
  float mu = s * (1.f / DD);
  float c0 = c0v - mu, c1 = c1v - mu;
  float q = c0 * c0 + c1 * c1;
#pragma unroll
  for (int off = 32; off > 0; off >>= 1) q += __shfl_xor(q, off);
  float rstd = rsqrtf(q * (1.f / DD) + EPSV);
  float2 gv = ((const float2*)gam)[lane];
  float2 tv = ((const float2*)bet)[lane];
  float h0 = fmaxf(fmaf(c0 * rstd, gv.x, tv.x), 0.f);
  float h1 = fmaxf(fmaf(c1 * rstd, gv.y, tv.y), 0.f);
  hls[wv * 64 + lane] = pk(h0, h1);
  if (lane == 0) dvs[wv] = di;
  __syncthreads();
  // epilogue: xwd2 rows = h @ W2 * dinv
#pragma unroll
  for (int cti = 0; cti < 2; ++cti) {
    int ct = wv * 2 + cti;
    f32x4 acc = {0.f, 0.f, 0.f, 0.f};
#pragma unroll
    for (int ks = 0; ks < 4; ++ks) {
      U4S8 ua, ub;
      ua.u = *(const uint4*)&hls[(lane & 15) * 64 + ks * 16 + ((lane >> 4) << 2)];
      ub.u = W2f[(ct * 4 + ks) * 64 + lane];
      acc = __builtin_amdgcn_mfma_f32_16x16x32_bf16(ua.s, ub.s, acc, 0, 0, 0);
    }
    if (lane < 16) {  // C rows 0-3 (the block's 4 node slots)
#pragma unroll
      for (int ri = 0; ri < 4; ++ri) {
        int node = blockIdx.x * 4 + ri;
        if (node < n)
          xwd2[(size_t)node * DD + ct * 16 + lane] = f2bf(acc[ri] * dvs[ri]);
      }
    }
  }
}

// ---------------- agg2: gather-sum + LN + SE + residual + ReLU -> fp32 out -------------

__global__ __launch_bounds__(256) void k_agg2(
    const ushort* __restrict__ xwd, const ushort* __restrict__ csr,
    const int* __restrict__ rowoff, const int* __restrict__ deg,
    const float* __restrict__ bias, const float* __restrict__ gam,
    const float* __restrict__ bet, const float* __restrict__ Ws,
    const float* __restrict__ bs, const float* __restrict__ We,
    const float* __restrict__ be, const float* __restrict__ xin,
    float* __restrict__ outp, int n) {
  int wv = threadIdx.x >> 6, lane = threadIdx.x & 63;
  int i = blockIdx.x * 4 + wv;
  if (i >= n) return;
  int start = rowoff[i], cnt = rowoff[i + 1] - start;
  float di = rsqrtf((float)deg[i] + 2.0f);
  const uint* xw32 = (const uint*)xwd;
  float acc0 = 0.f, acc1 = 0.f;
  edge_accum(xw32, csr, start, cnt, (uint)lane, acc0, acc1);
  uint su = xw32[((uint)i << 6) + lane];
  float2 bv = ((const float2*)bias)[lane];
  float c0v = fmaf(di, acc0 + 2.f * bflo(su), bv.x);
  float c1v = fmaf(di, acc1 + 2.f * bfhi(su), bv.y);
  float s = c0v + c1v;
#pragma unroll
  for (int off = 32; off > 0; off >>= 1) s += __shfl_xor(s, off);
  float mu = s * (1.f / DD);
  float c0 = c0v - mu, c1 = c1v - mu;
  float q = c0 * c0 + c1 * c1;
#pragma unroll
  for (int off = 32; off > 0; off >>= 1) q += __shfl_xor(q, off);
  float rstd = rsqrtf(q * (1.f / DD) + EPSV);
  float2 gv = ((const float2*)gam)[lane];
  float2 tv = ((const float2*)bet)[lane];
  float h0 = fmaf(c0 * rstd, gv.x, tv.x);
  float h1 = fmaf(c1 * rstd, gv.y, tv.y);
  float pj[HH];
  const float* wr0 = &Ws[(2 * lane) * HH];
  const float* wr1 = &Ws[(2 * lane + 1) * HH];
#pragma unroll
  for (int j = 0; j < HH; ++j) pj[j] = h0 * wr0[j] + h1 * wr1[j];
#pragma unroll
  for (int off = 32; off > 0; off >>= 1) {
#pragma unroll
    for (int j = 0; j < HH; ++j) pj[j] += __shfl_xor(pj[j], off);
  }
  float2 bev = ((const float2*)be)[lane];
  float wacc0 = bev.x, wacc1 = bev.y;
#pragma unroll
  for (int j = 0; j < HH; ++j) {
    float sj = fmaxf(pj[j] + bs[j], 0.f);
    float2 wev = ((const float2*)(We + j * DD))[lane];
    wacc0 = fmaf(sj, wev.x, wacc0);
    wacc1 = fmaf(sj, wev.y, wacc1);
  }
  float w0 = 1.f / (1.f + __expf(-wacc0));
  float w1 = 1.f / (1.f + __expf(-wacc1));
  float2 xr = ((const float2*)(xin + (size_t)i * DD))[lane];
  float2 o;
  o.x = fmaxf(fmaf(h0, w0, xr.x), 0.f);
  o.y = fmaxf(fmaf(h1, w1, xr.y), 0.f);
  ((float2*)(outp + (size_t)i * DD))[lane] = o;
}

// ---------------- launcher ----------------

extern "C" void kernel_launch(void* const* d_in, const int* in_sizes, int n_in,
                              void* d_out, int out_size, void* d_ws, size_t ws_size,
                              hipStream_t stream) {
  const float* x   = (const float*)d_in[0];
  const int*   ei  = (const int*)d_in[1];
  const float* W1  = (const float*)d_in[2];
  const float* b1  = (const float*)d_in[3];
  const float* g1  = (const float*)d_in[4];
  const float* be1 = (const float*)d_in[5];
  const float* W2  = (const float*)d_in[6];
  const float* b2  = (const float*)d_in[7];
  const float* g2  = (const float*)d_in[8];
  const float* be2 = (const float*)d_in[9];
  const float* Ws  = (const float*)d_in[10];
  const float* bs  = (const float*)d_in[11];
  const float* We  = (const float*)d_in[12];
  const float* bee = (const float*)d_in[13];
  float* outp = (float*)d_out;

  int n    = in_sizes[0] / DD;
  int ecnt = in_sizes[1] / 2;
  const int* src = ei;
  const int* dst = ei + ecnt;

  size_t maxent = (size_t)ecnt + 8 * (size_t)n + 64;

  char* w = (char*)d_ws;
  ushort* xwd    = (ushort*)w; w += (size_t)(n + 1) * DD * 2;  // row n = zero row
  ushort* xwd2   = (ushort*)w; w += (size_t)(n + 1) * DD * 2;  // row n = zero row
  int*    deg    = (int*)w;    w += (size_t)n * 4;
  int*    cursor = (int*)w;    w += (size_t)n * 4;
  int*    rowoff = (int*)w;    w += (size_t)(n + 1) * 4;
  w = (char*)(((size_t)w + 15) & ~(size_t)15);
  uint4*  W1f    = (uint4*)w;  w += 2048 * 16;
  uint4*  W2f    = (uint4*)w;  w += 2048 * 16;
  u64*    bsum   = (u64*)w;    w += 64 * 8;
  int*    bktB   = (int*)w;    w += NB * 4;
  int*    bktC   = (int*)w;    w += NB * 4;
  w = (char*)(((size_t)w + 15) & ~(size_t)15);
  uint*   pairs  = (uint*)w;   w += ((size_t)ecnt + 64) * 4;
  w = (char*)(((size_t)w + 15) & ~(size_t)15);
  ushort* csr    = (ushort*)w; w += maxent * 2;

  hipMemsetAsync(deg, 0, (size_t)n * 4, stream);
  hipMemsetAsync(xwd + (size_t)n * DD, 0, DD * 2, stream);
  hipMemsetAsync(xwd2 + (size_t)n * DD, 0, DD * 2, stream);

  const int TB = 256;
  k_hist_prep<<<2048, TB, 0, stream>>>(dst, deg, ecnt, W1, W2, W1f, W2f);
  int nb = (n + SCAN_T * SCAN_I - 1) / (SCAN_T * SCAN_I);
  k_scan1<<<nb, SCAN_T, 0, stream>>>(deg, bsum, n);
  k_scan2<<<nb, SCAN_T, 0, stream>>>(deg, bsum, rowoff, cursor, bktB, bktC, n);

  int gblocks = ((n + 63) / 64) * 2;
  int abloks = (ecnt + TILE - 1) / TILE;
  k_gemm1_bucket<<<abloks + gblocks, TB, 0, stream>>>(
      x, W1f, deg, xwd, n, src, dst, bktC, pairs, ecnt, abloks, gblocks);
  k_csrb<<<NB, TB, 0, stream>>>(pairs, bktB, rowoff, deg, cursor, csr, n, ecnt);

  int nb4 = (n + 3) / 4;
  k_agg1f<<<nb4, TB, 0, stream>>>(xwd, csr, rowoff, deg, b1, g1, be1, W2f, xwd2, n);
  k_agg2<<<nb4, TB, 0, stream>>>(xwd2, csr, rowoff, deg, b2, g2, be2,
                                 Ws, bs, We, bee, x, outp, n);
}